// Round 2
// baseline (1774.061 us; speedup 1.0000x reference)
//
#include <hip/hip_runtime.h>
#include <math.h>

namespace {
constexpr int NROWS = 16384;        // 16*32*32
constexpr int DDIM  = 256;
constexpr int KCODES = 8192;
constexpr int BM = 64;              // rows per block
constexpr int BN = 64;              // codes per chunk
constexpr int NCHUNK = KCODES / BN; // 128
constexpr int BSTR = 257;           // padded LDS stride for B (bank-conflict-free scalar reads)
constexpr size_t LOSS_OFF = (size_t)16 * 256 * 32 * 32;  // 4194304
constexpr size_t IDX_OFF  = LOSS_OFF + 1;
}

// One block = 256 threads = 4 waves, handles 64 consecutive flat rows (all in same b).
// A (z rows) staged transposed in LDS once; B (codes) streamed in 64-code chunks.
// Each thread computes a 4x4 microtile of dot products, tracks per-row running argmin.
__global__ __launch_bounds__(256, 1)
void vq_main_kernel(const float* __restrict__ z, const float* __restrict__ w,
                    float* __restrict__ out, float* __restrict__ part)
{
    __shared__ float At[DDIM][BM];     // 64 KB  z tile, transposed: At[d][r]
    __shared__ float Bt[BN][BSTR];     // ~64.3 KB  codes chunk: Bt[k][d], stride 257
    __shared__ float zn_s[BM];         // |z_r|^2
    __shared__ float wn4[BM][5];       // per-code |w|^2 partials (4 quarters)
    __shared__ float cmin[BM][17];     // argmin reduction candidates
    __shared__ int   cidx[BM][17];
    __shared__ int   fidx_s[BM];

    const int t = threadIdx.x;
    const int n0 = blockIdx.x * BM;
    const int bb = n0 >> 10;           // batch index (1024 rows per b)
    const int rem0 = n0 & 1023;        // h*32+w offset
    const float* zbase = z + (size_t)bb * DDIM * 1024 + rem0;

    // ---- stage A transposed: At[d][r] = z[(bb*256+d)*1024 + rem0 + r]  (coalesced) ----
    // 4096 float4 tasks: d = tau>>4 (0..255), r4 = (tau&15)*4 (0..60)
    #pragma unroll
    for (int it = 0; it < 16; ++it) {
        int tau = t + it * 256;
        int d = tau >> 4;
        int r4 = (tau & 15) << 2;
        float4 v = *reinterpret_cast<const float4*>(zbase + (size_t)d * 1024 + r4);
        *reinterpret_cast<float4*>(&At[d][r4]) = v;
    }
    __syncthreads();

    // ---- |z|^2 per row (threads 0..63) ----
    if (t < BM) {
        float s = 0.f;
        #pragma unroll 8
        for (int d = 0; d < DDIM; ++d) { float v = At[d][t]; s = fmaf(v, v, s); }
        zn_s[t] = s;   // read only after later barriers
    }

    const int ty = t >> 4, tx = t & 15;    // 16x16 thread grid, 4x4 microtile
    float rmin[4];
    int   ridx[4];
    #pragma unroll
    for (int i = 0; i < 4; ++i) { rmin[i] = INFINITY; ridx[i] = 0; }

    for (int nc = 0; nc < NCHUNK; ++nc) {
        // ---- stage B chunk: 64 codes x 256 d ----
        // 4096 float4 tasks: k = tau>>6 (0..63), d4 = (tau&63)*4 (0..252)
        // (wave-coalesced: one wave = one full 1KB code row)
        const float* wb = w + (size_t)nc * BN * DDIM;
        #pragma unroll
        for (int it = 0; it < 16; ++it) {
            int tau = t + it * 256;
            int k = tau >> 6;
            int d4 = (tau & 63) << 2;
            float4 v = *reinterpret_cast<const float4*>(wb + (size_t)k * DDIM + d4);
            Bt[k][d4 + 0] = v.x; Bt[k][d4 + 1] = v.y;
            Bt[k][d4 + 2] = v.z; Bt[k][d4 + 3] = v.w;
        }
        __syncthreads();

        // ---- |w|^2 partials: thread (k = t&63, q = t>>6) sums quarter q of code k ----
        {
            int k = t & 63, q = t >> 6;
            float s = 0.f;
            const int d0 = q * 64;
            #pragma unroll 8
            for (int d = 0; d < 64; ++d) { float v = Bt[k][d0 + d]; s = fmaf(v, v, s); }
            wn4[k][q] = s;
        }

        // ---- 4x4 microtile dot products over D=256 ----
        float acc[4][4];
        #pragma unroll
        for (int i = 0; i < 4; ++i)
            #pragma unroll
            for (int j = 0; j < 4; ++j) acc[i][j] = 0.f;

        #pragma unroll 8
        for (int kk = 0; kk < DDIM; ++kk) {
            float a[4], bv[4];
            *reinterpret_cast<float4*>(a) =
                *reinterpret_cast<const float4*>(&At[kk][ty << 2]);   // ds_read_b128, broadcast
            #pragma unroll
            for (int j = 0; j < 4; ++j) bv[j] = Bt[(tx << 2) + j][kk]; // 16 banks, broadcast
            #pragma unroll
            for (int i = 0; i < 4; ++i)
                #pragma unroll
                for (int j = 0; j < 4; ++j) acc[i][j] = fmaf(a[i], bv[j], acc[i][j]);
        }
        __syncthreads();   // wn4 visible; Bt safe to overwrite next chunk

        // ---- score = |w|^2 - 2*dot ; running argmin (first-min tie rule) ----
        #pragma unroll
        for (int j = 0; j < 4; ++j) {
            int c = (tx << 2) + j;
            float wn = wn4[c][0] + wn4[c][1] + wn4[c][2] + wn4[c][3];
            int gidx = nc * BN + c;
            #pragma unroll
            for (int i = 0; i < 4; ++i) {
                float s = fmaf(-2.f, acc[i][j], wn);
                if (s < rmin[i]) { rmin[i] = s; ridx[i] = gidx; }
            }
        }
    }

    // ---- cross-tx argmin reduction ----
    #pragma unroll
    for (int i = 0; i < 4; ++i) {
        cmin[(ty << 2) + i][tx] = rmin[i];
        cidx[(ty << 2) + i][tx] = ridx[i];
    }
    __syncthreads();

    float dist = 0.f;
    if (t < BM) {
        float bestv = cmin[t][0]; int besti = cidx[t][0];
        #pragma unroll
        for (int x = 1; x < 16; ++x) {
            float v = cmin[t][x]; int ix = cidx[t][x];
            if (v < bestv || (v == bestv && ix < besti)) { bestv = v; besti = ix; }
        }
        fidx_s[t] = besti;
        out[IDX_OFF + n0 + t] = (float)besti;            // indices as float
        dist = zn_s[t] + bestv;                          // |z|^2 + (|w|^2 - 2 z.w)
    }
    // deterministic per-block loss partial (wave 0 only; threads 0..63 = lanes 0..63)
    if (t < 64) {
        for (int off = 32; off > 0; off >>= 1) dist += __shfl_down(dist, off, 64);
        if (t == 0) part[blockIdx.x] = dist;
    }
    __syncthreads();

    // ---- scatter z_q: out[(bb*256+d)*1024 + rem0 + r] = w[idx_r][d] ----
    {
        int r = t & 63, dq = t >> 6;   // wave dq handles d-quarter dq, lane = row
        int idx = fidx_s[r];
        const float4* wrow = reinterpret_cast<const float4*>(w + (size_t)idx * DDIM + dq * 64);
        float* obase = out + ((size_t)bb * DDIM + dq * 64) * 1024 + rem0 + r;
        #pragma unroll
        for (int d4 = 0; d4 < 16; ++d4) {
            float4 v = wrow[d4];
            obase[(size_t)(d4 * 4 + 0) * 1024] = v.x;
            obase[(size_t)(d4 * 4 + 1) * 1024] = v.y;
            obase[(size_t)(d4 * 4 + 2) * 1024] = v.z;
            obase[(size_t)(d4 * 4 + 3) * 1024] = v.w;
        }
    }
}

// Sum 256 per-block loss partials -> scalar loss (deterministic).
__global__ void vq_finish_kernel(const float* __restrict__ part, float* __restrict__ out)
{
    __shared__ float s4[4];
    int t = threadIdx.x;
    float v = part[t];
    for (int off = 32; off > 0; off >>= 1) v += __shfl_down(v, off, 64);
    if ((t & 63) == 0) s4[t >> 6] = v;
    __syncthreads();
    if (t == 0) {
        float tot = s4[0] + s4[1] + s4[2] + s4[3];
        out[LOSS_OFF] = 0.25f * tot / ((float)NROWS * (float)DDIM);
    }
}

extern "C" void kernel_launch(void* const* d_in, const int* in_sizes, int n_in,
                              void* d_out, int out_size, void* d_ws, size_t ws_size,
                              hipStream_t stream) {
    const float* z = (const float*)d_in[0];
    const float* w = (const float*)d_in[1];
    float* out = (float*)d_out;
    float* part = (float*)d_ws;          // 256 floats of scratch
    vq_main_kernel<<<NROWS / BM, 256, 0, stream>>>(z, w, out, part);
    vq_finish_kernel<<<1, 256, 0, stream>>>(part, out);
}

// Round 3
// 190.024 us; speedup vs baseline: 9.3360x; 9.3360x over previous
//
#include <hip/hip_runtime.h>
#include <math.h>

typedef _Float16 half8 __attribute__((ext_vector_type(8)));
typedef float f32x4 __attribute__((ext_vector_type(4)));

namespace {
constexpr int NROWS = 16384;        // 16*32*32
constexpr int DDIM  = 256;
constexpr int KCODES = 8192;
constexpr size_t LOSS_OFF = (size_t)16 * 256 * 32 * 32;  // 4194304
constexpr size_t IDX_OFF  = LOSS_OFF + 1;
constexpr float LSCALE = 2048.f;
constexpr float LINV   = 1.f / 2048.f;
// workspace layout (bytes)
constexpr size_t WS_WH   = 0;                    // 4 MB fp16 hi plane, swizzled
constexpr size_t WS_WL   = 4194304;              // 4 MB fp16 lo*2048 plane
constexpr size_t WS_WN   = 8388608;              // 8192 f32 |w|^2
constexpr size_t WS_PV   = WS_WN + 32768;        // 2*16384 f32 partial min values
constexpr size_t WS_PI   = WS_PV + 131072;       // 2*16384 i32 partial min indices
constexpr size_t WS_PART = WS_PI + 131072;       // 256 f32 loss partials
constexpr size_t WS_NEED = WS_PART + 1024;       // ~8.7 MB
}

// ============================================================================
// Pre-convert codebook: fp32 -> fp16 (hi, lo*2048) planes, swizzled for
// global_load_lds-linear staging + conflict-free ds_read_b128 B-frag reads.
// Also computes |w|^2 per code (deterministic shfl reduce).
// Plane layout: [tile=code>>7][kc=k>>6][c=code&127][granule g^(c&7)] x 16B
// ============================================================================
__global__ __launch_bounds__(256)
void vq_prep(const float* __restrict__ w, unsigned char* __restrict__ ws)
{
    const int tau = blockIdx.x * 256 + threadIdx.x;   // 0..262143
    const int gcode = tau >> 5;                       // 0..8191
    const int sub = tau & 31;
    const int kc = sub >> 3, g = sub & 7;
    const float* src = w + (size_t)gcode * 256 + kc * 64 + g * 8;
    float x[8];
    *reinterpret_cast<float4*>(x)     = *reinterpret_cast<const float4*>(src);
    *reinterpret_cast<float4*>(x + 4) = *reinterpret_cast<const float4*>(src + 4);
    half8 hi, lo;
    float sq = 0.f;
    #pragma unroll
    for (int j = 0; j < 8; ++j) {
        float v = x[j];
        sq = fmaf(v, v, sq);
        _Float16 h = (_Float16)v;
        hi[j] = h;
        lo[j] = (_Float16)((v - (float)h) * LSCALE);
    }
    const size_t off = (size_t)(gcode >> 7) * 65536 + (size_t)kc * 16384
                     + (size_t)(gcode & 127) * 128 + (size_t)((g ^ (gcode & 7)) << 4);
    *reinterpret_cast<half8*>(ws + WS_WH + off) = hi;
    *reinterpret_cast<half8*>(ws + WS_WL + off) = lo;
    // |w|^2: reduce over the 32 threads of this code
    #pragma unroll
    for (int o = 16; o > 0; o >>= 1) sq += __shfl_down(sq, o, 32);
    if ((threadIdx.x & 31) == 0)
        *reinterpret_cast<float*>(ws + WS_WN + (size_t)gcode * 4) = sq;
}

// ============================================================================
// Main MFMA kernel. Block = 512 thr (8 waves, 4M x 2N), 128 rows x 4096 codes.
// grid 256: bid&127 = row group, bid>>7 = code half.
// LDS: [0,64K) zh staging -> 4x16KB W-chunk arena; [64K,128K) zl resident.
// Per code-tile (128 codes): 8 chunks (4 kc x {hi,lo}), pipelined depth-3,
// counted vmcnt, raw barriers. dot = accM + accC/2048.
// ============================================================================
__global__ __launch_bounds__(512, 2)
void vq_mfma(const float* __restrict__ z, unsigned char* __restrict__ ws)
{
    __shared__ __align__(16) unsigned char lds[131072];

    const int t = threadIdx.x;
    const int lane = t & 63;
    const int wv = t >> 6;          // 0..7
    const int wm = wv >> 1;         // 0..3: row group of 32
    const int wng = wv & 1;         // 0..1: code group of 64
    const int rl = lane & 15, lh = lane >> 4;
    const int bid = blockIdx.x;
    const int rg = bid & 127;
    const int half = bid >> 7;

    const int n0 = rg * 128;
    const int bb = n0 >> 10;
    const int rem0 = n0 & 1023;
    const float* zbase = z + (size_t)bb * 256 * 1024 + rem0;

    // ---- stage Z: fp32 -> (hi, lo*2048) fp16 planes, swizzled ----
    {
        const int r = t & 127;
        const int ob = t >> 7;               // 0..3
        #pragma unroll
        for (int i = 0; i < 8; ++i) {
            const int o = i * 4 + ob;        // k-octet 0..31
            half8 hi, lo;
            #pragma unroll
            for (int j = 0; j < 8; ++j) {
                float v = zbase[(size_t)(o * 8 + j) * 1024 + r];
                _Float16 h = (_Float16)v;
                hi[j] = h;
                lo[j] = (_Float16)((v - (float)h) * LSCALE);
            }
            const int zoff = r * 512 + ((o ^ (r & 7)) << 4);
            *reinterpret_cast<half8*>(lds + zoff) = hi;
            *reinterpret_cast<half8*>(lds + 65536 + zoff) = lo;
        }
    }
    __syncthreads();

    // ---- hoist zh fragments to registers: ah[kc][kstep][m] ----
    half8 ah[4][2][2];
    #pragma unroll
    for (int kc = 0; kc < 4; ++kc)
        #pragma unroll
        for (int ks = 0; ks < 2; ++ks)
            #pragma unroll
            for (int m = 0; m < 2; ++m) {
                const int r = wm * 32 + m * 16 + rl;
                const int g = kc * 8 + ks * 4 + lh;
                ah[kc][ks][m] = *reinterpret_cast<const half8*>(
                    lds + r * 512 + ((g ^ (r & 7)) << 4));
            }
    __syncthreads();    // zh region now free -> W-chunk arena

    auto issue_chunk = [&](int nt, int c) {
        const int p = c & 1, kc = c >> 1;
        const unsigned char* src = ws + (p ? WS_WL : WS_WH)
            + (size_t)(half * 32 + nt) * 65536 + (size_t)kc * 16384;
        unsigned char* dstbase = lds + (c & 3) * 16384;
        #pragma unroll
        for (int i = 0; i < 2; ++i) {
            const unsigned char* g = src + (size_t)(wv * 128 + i * 64 + lane) * 16;
            void* l = dstbase + (size_t)(wv * 128 + i * 64) * 16;
            __builtin_amdgcn_global_load_lds(
                (const __attribute__((address_space(1))) unsigned int*)g,
                (__attribute__((address_space(3))) unsigned int*)l, 16, 0, 0);
        }
    };

    float bv[2][4];
    int   bix[2][4];
    #pragma unroll
    for (int m = 0; m < 2; ++m)
        #pragma unroll
        for (int r = 0; r < 4; ++r) { bv[m][r] = INFINITY; bix[m][r] = 0; }

    for (int nt = 0; nt < 32; ++nt) {
        f32x4 accM[2][4], accC[2][4];
        #pragma unroll
        for (int m = 0; m < 2; ++m)
            #pragma unroll
            for (int n = 0; n < 4; ++n) {
                accM[m][n] = (f32x4)0.f;
                accC[m][n] = (f32x4)0.f;
            }
        issue_chunk(nt, 0); issue_chunk(nt, 1); issue_chunk(nt, 2);

        #pragma unroll
        for (int c = 0; c < 8; ++c) {
            if (c <= 5)      asm volatile("s_waitcnt vmcnt(4)" ::: "memory");
            else if (c == 6) asm volatile("s_waitcnt vmcnt(2)" ::: "memory");
            else             asm volatile("s_waitcnt vmcnt(0)" ::: "memory");
            __builtin_amdgcn_s_barrier();
            asm volatile("" ::: "memory");

            const unsigned char* wb = lds + (c & 3) * 16384;
            const int kc = c >> 1;
            if ((c & 1) == 0) {
                // hi-plane chunk: S0 (zh x wh -> accM), S2 (zl x wh -> accC)
                #pragma unroll
                for (int ks = 0; ks < 2; ++ks) {
                    half8 bf[4];
                    #pragma unroll
                    for (int n = 0; n < 4; ++n) {
                        const int cc = wng * 64 + n * 16 + rl;
                        const int gg = ks * 4 + lh;
                        bf[n] = *reinterpret_cast<const half8*>(
                            wb + cc * 128 + ((gg ^ (cc & 7)) << 4));
                    }
                    #pragma unroll
                    for (int m = 0; m < 2; ++m)
                        #pragma unroll
                        for (int n = 0; n < 4; ++n)
                            accM[m][n] = __builtin_amdgcn_mfma_f32_16x16x32_f16(
                                ah[kc][ks][m], bf[n], accM[m][n], 0, 0, 0);
                    #pragma unroll
                    for (int m = 0; m < 2; ++m) {
                        const int r = wm * 32 + m * 16 + rl;
                        const int g = kc * 8 + ks * 4 + lh;
                        half8 al = *reinterpret_cast<const half8*>(
                            lds + 65536 + r * 512 + ((g ^ (r & 7)) << 4));
                        #pragma unroll
                        for (int n = 0; n < 4; ++n)
                            accC[m][n] = __builtin_amdgcn_mfma_f32_16x16x32_f16(
                                al, bf[n], accC[m][n], 0, 0, 0);
                    }
                }
            } else {
                // lo-plane chunk: S1 (zh x wl -> accC)
                #pragma unroll
                for (int ks = 0; ks < 2; ++ks) {
                    half8 bf[4];
                    #pragma unroll
                    for (int n = 0; n < 4; ++n) {
                        const int cc = wng * 64 + n * 16 + rl;
                        const int gg = ks * 4 + lh;
                        bf[n] = *reinterpret_cast<const half8*>(
                            wb + cc * 128 + ((gg ^ (cc & 7)) << 4));
                    }
                    #pragma unroll
                    for (int m = 0; m < 2; ++m)
                        #pragma unroll
                        for (int n = 0; n < 4; ++n)
                            accC[m][n] = __builtin_amdgcn_mfma_f32_16x16x32_f16(
                                ah[kc][ks][m], bf[n], accC[m][n], 0, 0, 0);
                }
            }
            __builtin_amdgcn_s_barrier();
            asm volatile("" ::: "memory");
            if (c < 5) issue_chunk(nt, c + 3);
        }

        // ---- tile epilogue: score = |w|^2 - 2*dot ; running argmin ----
        const int codebase = (half * 32 + nt) * 128 + wng * 64;
        #pragma unroll
        for (int n = 0; n < 4; ++n) {
            const int code = codebase + n * 16 + rl;
            const float wnv = *reinterpret_cast<const float*>(ws + WS_WN + (size_t)code * 4);
            #pragma unroll
            for (int m = 0; m < 2; ++m)
                #pragma unroll
                for (int rr = 0; rr < 4; ++rr) {
                    float dot = accM[m][n][rr] + accC[m][n][rr] * LINV;
                    float s = fmaf(-2.f, dot, wnv);
                    if (s < bv[m][rr]) { bv[m][rr] = s; bix[m][rr] = code; }
                }
        }
    }

    // ---- cross-lane argmin reduce (16 lanes sharing a row), then LDS ----
    #pragma unroll
    for (int m = 0; m < 2; ++m)
        #pragma unroll
        for (int rr = 0; rr < 4; ++rr) {
            float v = bv[m][rr]; int ix = bix[m][rr];
            #pragma unroll
            for (int o = 8; o > 0; o >>= 1) {
                float ov = __shfl_xor(v, o, 16);
                int   oi = __shfl_xor(ix, o, 16);
                if (ov < v || (ov == v && oi < ix)) { v = ov; ix = oi; }
            }
            if (rl == 0) {
                const int row = wm * 32 + m * 16 + lh * 4 + rr;
                *reinterpret_cast<float*>(lds + (size_t)(row * 2 + wng) * 8) = v;
                *reinterpret_cast<int*>(lds + (size_t)(row * 2 + wng) * 8 + 4) = ix;
            }
        }
    __syncthreads();
    if (t < 128) {
        float v0 = *reinterpret_cast<float*>(lds + (size_t)(t * 2 + 0) * 8);
        int   i0 = *reinterpret_cast<int*>(lds + (size_t)(t * 2 + 0) * 8 + 4);
        float v1 = *reinterpret_cast<float*>(lds + (size_t)(t * 2 + 1) * 8);
        int   i1 = *reinterpret_cast<int*>(lds + (size_t)(t * 2 + 1) * 8 + 4);
        float v = v0; int ix = i0;
        if (v1 < v || (v1 == v && i1 < ix)) { v = v1; ix = i1; }
        const int grow = n0 + t;
        *reinterpret_cast<float*>(ws + WS_PV + ((size_t)half * 16384 + grow) * 4) = v;
        *reinterpret_cast<int*>(ws + WS_PI + ((size_t)half * 16384 + grow) * 4) = ix;
    }
}

// ============================================================================
// Merge halves, write indices, gather z_q, direct loss partial sum.
// ============================================================================
__global__ __launch_bounds__(256)
void vq_gather(const float* __restrict__ z, const float* __restrict__ w,
               const unsigned char* __restrict__ ws, float* __restrict__ out,
               float* __restrict__ part)
{
    __shared__ int sidx[64];
    __shared__ float s4[4];
    const int t = threadIdx.x;
    const int n0 = blockIdx.x * 64;
    const int bb = n0 >> 10, rem0 = n0 & 1023;
    const float* pv = reinterpret_cast<const float*>(ws + WS_PV);
    const int*   pi = reinterpret_cast<const int*>(ws + WS_PI);
    if (t < 64) {
        const int grow = n0 + t;
        float v0 = pv[grow],        v1 = pv[16384 + grow];
        int   i0 = pi[grow],        i1 = pi[16384 + grow];
        int ix = (v1 < v0 || (v1 == v0 && i1 < i0)) ? i1 : i0;
        sidx[t] = ix;
        out[IDX_OFF + grow] = (float)ix;
    }
    __syncthreads();
    const int r = t & 63, dq = t >> 6;
    const int idx = sidx[r];
    const float4* wrow = reinterpret_cast<const float4*>(w + (size_t)idx * 256 + dq * 64);
    const float* zb = z   + ((size_t)bb * 256 + dq * 64) * 1024 + rem0 + r;
    float*       ob = out + ((size_t)bb * 256 + dq * 64) * 1024 + rem0 + r;
    float acc = 0.f;
    #pragma unroll
    for (int d4 = 0; d4 < 16; ++d4) {
        float4 v = wrow[d4];
        float z0 = zb[(size_t)(d4 * 4 + 0) * 1024];
        float z1 = zb[(size_t)(d4 * 4 + 1) * 1024];
        float z2 = zb[(size_t)(d4 * 4 + 2) * 1024];
        float z3 = zb[(size_t)(d4 * 4 + 3) * 1024];
        ob[(size_t)(d4 * 4 + 0) * 1024] = v.x;
        ob[(size_t)(d4 * 4 + 1) * 1024] = v.y;
        ob[(size_t)(d4 * 4 + 2) * 1024] = v.z;
        ob[(size_t)(d4 * 4 + 3) * 1024] = v.w;
        float d0 = z0 - v.x, d1 = z1 - v.y, d2 = z2 - v.z, d3 = z3 - v.w;
        acc = fmaf(d0, d0, acc); acc = fmaf(d1, d1, acc);
        acc = fmaf(d2, d2, acc); acc = fmaf(d3, d3, acc);
    }
    #pragma unroll
    for (int o = 32; o > 0; o >>= 1) acc += __shfl_down(acc, o, 64);
    if ((t & 63) == 0) s4[t >> 6] = acc;
    __syncthreads();
    if (t == 0) part[blockIdx.x] = s4[0] + s4[1] + s4[2] + s4[3];
}

__global__ void vq_finish_kernel(const float* __restrict__ part, float* __restrict__ out)
{
    __shared__ float s4[4];
    int t = threadIdx.x;
    float v = part[t];
    #pragma unroll
    for (int off = 32; off > 0; off >>= 1) v += __shfl_down(v, off, 64);
    if ((t & 63) == 0) s4[t >> 6] = v;
    __syncthreads();
    if (t == 0) {
        float tot = s4[0] + s4[1] + s4[2] + s4[3];
        out[LOSS_OFF] = 0.25f * tot / ((float)NROWS * (float)DDIM);
    }
}

// ============================================================================
// Fallback (proven round-2 fp32 path) used only when ws_size is too small.
// ============================================================================
namespace fb {
constexpr int BM = 64, BN = 64, NCHUNK = KCODES / BN, BSTR = 257;
}
__global__ __launch_bounds__(256, 1)
void vq_main_fp32(const float* __restrict__ z, const float* __restrict__ w,
                  float* __restrict__ out, float* __restrict__ part)
{
    using namespace fb;
    __shared__ float At[DDIM][BM];
    __shared__ float Bt[BN][BSTR];
    __shared__ float zn_s[BM];
    __shared__ float wn4[BM][5];
    __shared__ float cmin[BM][17];
    __shared__ int   cidx[BM][17];
    __shared__ int   fidx_s[BM];

    const int t = threadIdx.x;
    const int n0 = blockIdx.x * BM;
    const int bb = n0 >> 10;
    const int rem0 = n0 & 1023;
    const float* zbase = z + (size_t)bb * DDIM * 1024 + rem0;

    #pragma unroll
    for (int it = 0; it < 16; ++it) {
        int tau = t + it * 256;
        int d = tau >> 4;
        int r4 = (tau & 15) << 2;
        float4 v = *reinterpret_cast<const float4*>(zbase + (size_t)d * 1024 + r4);
        *reinterpret_cast<float4*>(&At[d][r4]) = v;
    }
    __syncthreads();
    if (t < BM) {
        float s = 0.f;
        #pragma unroll 8
        for (int d = 0; d < DDIM; ++d) { float v = At[d][t]; s = fmaf(v, v, s); }
        zn_s[t] = s;
    }
    const int ty = t >> 4, tx = t & 15;
    float rmin[4]; int ridx[4];
    #pragma unroll
    for (int i = 0; i < 4; ++i) { rmin[i] = INFINITY; ridx[i] = 0; }

    for (int nc = 0; nc < NCHUNK; ++nc) {
        const float* wb = w + (size_t)nc * BN * DDIM;
        #pragma unroll
        for (int it = 0; it < 16; ++it) {
            int tau = t + it * 256;
            int k = tau >> 6;
            int d4 = (tau & 63) << 2;
            float4 v = *reinterpret_cast<const float4*>(wb + (size_t)k * DDIM + d4);
            Bt[k][d4 + 0] = v.x; Bt[k][d4 + 1] = v.y;
            Bt[k][d4 + 2] = v.z; Bt[k][d4 + 3] = v.w;
        }
        __syncthreads();
        {
            int k = t & 63, q = t >> 6;
            float s = 0.f;
            const int d0 = q * 64;
            #pragma unroll 8
            for (int d = 0; d < 64; ++d) { float v = Bt[k][d0 + d]; s = fmaf(v, v, s); }
            wn4[k][q] = s;
        }
        float acc[4][4];
        #pragma unroll
        for (int i = 0; i < 4; ++i)
            #pragma unroll
            for (int j = 0; j < 4; ++j) acc[i][j] = 0.f;
        #pragma unroll 8
        for (int kk = 0; kk < DDIM; ++kk) {
            float a[4], bvv[4];
            *reinterpret_cast<float4*>(a) =
                *reinterpret_cast<const float4*>(&At[kk][ty << 2]);
            #pragma unroll
            for (int j = 0; j < 4; ++j) bvv[j] = Bt[(tx << 2) + j][kk];
            #pragma unroll
            for (int i = 0; i < 4; ++i)
                #pragma unroll
                for (int j = 0; j < 4; ++j) acc[i][j] = fmaf(a[i], bvv[j], acc[i][j]);
        }
        __syncthreads();
        #pragma unroll
        for (int j = 0; j < 4; ++j) {
            int c = (tx << 2) + j;
            float wn = wn4[c][0] + wn4[c][1] + wn4[c][2] + wn4[c][3];
            int gidx = nc * BN + c;
            #pragma unroll
            for (int i = 0; i < 4; ++i) {
                float s = fmaf(-2.f, acc[i][j], wn);
                if (s < rmin[i]) { rmin[i] = s; ridx[i] = gidx; }
            }
        }
    }
    #pragma unroll
    for (int i = 0; i < 4; ++i) {
        cmin[(ty << 2) + i][tx] = rmin[i];
        cidx[(ty << 2) + i][tx] = ridx[i];
    }
    __syncthreads();
    float dist = 0.f;
    if (t < BM) {
        float bestv = cmin[t][0]; int besti = cidx[t][0];
        #pragma unroll
        for (int x = 1; x < 16; ++x) {
            float v = cmin[t][x]; int ix = cidx[t][x];
            if (v < bestv || (v == bestv && ix < besti)) { bestv = v; besti = ix; }
        }
        fidx_s[t] = besti;
        out[IDX_OFF + n0 + t] = (float)besti;
        dist = zn_s[t] + bestv;
    }
    if (t < 64) {
        #pragma unroll
        for (int off = 32; off > 0; off >>= 1) dist += __shfl_down(dist, off, 64);
        if (t == 0) part[blockIdx.x] = dist;
    }
    __syncthreads();
    {
        int r = t & 63, dq = t >> 6;
        int idx = fidx_s[r];
        const float4* wrow = reinterpret_cast<const float4*>(w + (size_t)idx * DDIM + dq * 64);
        float* obase = out + ((size_t)bb * DDIM + dq * 64) * 1024 + rem0 + r;
        #pragma unroll
        for (int d4 = 0; d4 < 16; ++d4) {
            float4 v = wrow[d4];
            obase[(size_t)(d4 * 4 + 0) * 1024] = v.x;
            obase[(size_t)(d4 * 4 + 1) * 1024] = v.y;
            obase[(size_t)(d4 * 4 + 2) * 1024] = v.z;
            obase[(size_t)(d4 * 4 + 3) * 1024] = v.w;
        }
    }
}

extern "C" void kernel_launch(void* const* d_in, const int* in_sizes, int n_in,
                              void* d_out, int out_size, void* d_ws, size_t ws_size,
                              hipStream_t stream) {
    const float* z = (const float*)d_in[0];
    const float* w = (const float*)d_in[1];
    float* out = (float*)d_out;
    if (ws_size >= WS_NEED) {
        unsigned char* ws = (unsigned char*)d_ws;
        float* part = reinterpret_cast<float*>(ws + WS_PART);
        vq_prep<<<1024, 256, 0, stream>>>(w, ws);
        vq_mfma<<<256, 512, 0, stream>>>(z, ws);
        vq_gather<<<256, 256, 0, stream>>>(z, w, ws, out, part);
        vq_finish_kernel<<<1, 256, 0, stream>>>(part, out);
    } else {
        float* part = (float*)d_ws;
        vq_main_fp32<<<NROWS / fb::BM, 256, 0, stream>>>(z, w, out, part);
        vq_finish_kernel<<<1, 256, 0, stream>>>(part, out);
    }
}